// Round 5
// baseline (1055.975 us; speedup 1.0000x reference)
//
#include <hip/hip_runtime.h>
#include <stdint.h>

// ---------------------------------------------------------------------------
// SemanticMemoryModule: out = softmax((H@Wp + bp) @ C^T) @ C @ Wo + bo
// R5 dtype model: inputs FP32 (proven by R1-R4 NaN evidence), output FP32
// (R4's 7.5 error == bf16-written-into-fp32-read signature).
// fp32 operands -> bf16 hi/lo planes; 3 cross terms folded into one K=6144
// GEMM via block-uniform k remaps:
//   A planes [Xh,Xh,Xl]: kA = k<2048 ? k : k-2048   (layout [Xh|Xl], lda 4096)
//   B planes [Yh,Yl,Yh]: kB = k<4096 ? k : k-4096   (layout [Yh|Yl], ldb 4096)
// Pipeline:
//   C2,Wp2 = split(C),split(Wp); WoT2 = transpose+split(Wo)  (d_out head scratch)
//   WpC2[c,:] = hi/lo(sum_e C[c,e] Wp[d,e])  [1024 x 4096] bf16  (ws)
//   CWT[d,c]  = sum_e Wo[e,d] C[c,e]         [2048 x 1024] bf16  (ws)
//   sb[c]     = sum_e bp[e] C[c,e]           fp32
//   per S-chunk: H2=split(Hc); scores = H2 (x) WpC2 + sb (fp32, K=6144)
//                probs = softmax(scores) -> bf16 in-place
//                out = probs @ CWT^T + bo -> FP32
// d_out is 128MB fp32; head [0,40MB) = prepass scratch (stream-ordered:
// consumed by prepass GEMMs before chunk 0's final GEMM writes it).
// ws floor: 12.07MB + cr*12KB, cr adaptive >= 128.
// ---------------------------------------------------------------------------

typedef unsigned short ushort_t;
typedef __bf16 bf16x8  __attribute__((ext_vector_type(8)));
typedef short  shortx8 __attribute__((ext_vector_type(8)));
typedef short  shortx4 __attribute__((ext_vector_type(4)));
typedef float  floatx4 __attribute__((ext_vector_type(4)));

__device__ __forceinline__ float bf2f(ushort_t u) {
  union { unsigned u; float f; } x; x.u = ((unsigned)u) << 16; return x.f;
}
__device__ __forceinline__ ushort_t f2bf(float f) {
  union { float f; unsigned u; } x; x.f = f;
  unsigned r = x.u + 0x7FFFu + ((x.u >> 16) & 1u);   // RNE
  return (ushort_t)(r >> 16);
}

// ---------------------------------------------------------------------------
// out[M,N] = A[M,K] (x) Bt[N,K]^T, 128x128 tile, BK=64, 4 waves, bf16 MFMA.
// Block-uniform k remaps: kA = k<athr ? k : k-asub; kB likewise.
// MODE 0: fp32 out + fp32 bias[col] (biasp may be null)
// MODE 1: bf16 out, no bias
// MODE 2: bf16 hi at [row*ldo+col], lo at [row*ldo+2048+col]
// ---------------------------------------------------------------------------
template<int MODE>
__global__ __launch_bounds__(256) void gemm_bt(
    const ushort_t* __restrict__ A, const ushort_t* __restrict__ Bt,
    void* __restrict__ outp, const float* __restrict__ biasp,
    int K, int lda, int ldb, int ldo, int Mvalid, int Nvalid,
    int athr, int asub, int bthr, int bsub)
{
  __shared__ __align__(16) ushort_t As[128 * 64];
  __shared__ __align__(16) ushort_t Bs[128 * 64];

  const int tid  = threadIdx.x;
  const int wave = tid >> 6;
  const int lane = tid & 63;
  const int m0 = blockIdx.x * 128;
  const int n0 = blockIdx.y * 128;

  const int rg = tid >> 3;            // staging row in 32-row group
  const int ck = (tid & 7) * 8;       // staging k-chunk (16B)

  floatx4 acc[4][4] = {};
  const int wm = (wave >> 1) * 64;
  const int wn = (wave & 1) * 64;
  const int fr = lane & 15;
  const int fq = lane >> 4;

  shortx8 ra[4], rb[4];
  {
#pragma unroll
    for (int s = 0; s < 4; ++s) {
      int row = s * 32 + rg;
      int mg = min(m0 + row, Mvalid - 1);
      ra[s] = *(const shortx8*)&A[(size_t)mg * lda + ck];
      int ng = min(n0 + row, Nvalid - 1);
      rb[s] = *(const shortx8*)&Bt[(size_t)ng * ldb + ck];
    }
  }

  for (int k0 = 0; k0 < K; k0 += 64) {
    __syncthreads();
#pragma unroll
    for (int s = 0; s < 4; ++s) {
      int row = s * 32 + rg;
      *(shortx8*)&As[row * 64 + ck] = ra[s];
      *(shortx8*)&Bs[row * 64 + ck] = rb[s];
    }
    __syncthreads();

    int kn = k0 + 64;
    if (kn < K) {                      // block-uniform
      int ka0 = (kn < athr) ? kn : kn - asub;
      int kb0 = (kn < bthr) ? kn : kn - bsub;
#pragma unroll
      for (int s = 0; s < 4; ++s) {
        int row = s * 32 + rg;
        int mg = min(m0 + row, Mvalid - 1);
        ra[s] = *(const shortx8*)&A[(size_t)mg * lda + ka0 + ck];
        int ng = min(n0 + row, Nvalid - 1);
        rb[s] = *(const shortx8*)&Bt[(size_t)ng * ldb + kb0 + ck];
      }
    }

#pragma unroll
    for (int kk = 0; kk < 2; ++kk) {
      shortx8 a[4], b[4];
#pragma unroll
      for (int i = 0; i < 4; ++i)
        a[i] = *(const shortx8*)&As[(wm + i * 16 + fr) * 64 + kk * 32 + fq * 8];
#pragma unroll
      for (int j = 0; j < 4; ++j)
        b[j] = *(const shortx8*)&Bs[(wn + j * 16 + fr) * 64 + kk * 32 + fq * 8];
#pragma unroll
      for (int i = 0; i < 4; ++i)
#pragma unroll
        for (int j = 0; j < 4; ++j)
          acc[i][j] = __builtin_amdgcn_mfma_f32_16x16x32_bf16(
              __builtin_bit_cast(bf16x8, a[i]), __builtin_bit_cast(bf16x8, b[j]),
              acc[i][j], 0, 0, 0);
    }
  }

  // D layout: col = lane&15 (n), row = quad*4 + r (m)   [m89/m91-verified]
#pragma unroll
  for (int i = 0; i < 4; ++i) {
#pragma unroll
    for (int j = 0; j < 4; ++j) {
      int col = n0 + wn + j * 16 + fr;
#pragma unroll
      for (int r = 0; r < 4; ++r) {
        int row = m0 + wm + i * 16 + fq * 4 + r;
        float v = acc[i][j][r];
        if (MODE == 0) {
          float b = biasp ? biasp[col] : 0.0f;
          ((float*)outp)[(size_t)row * ldo + col] = v + b;
        } else if (MODE == 1) {
          ((ushort_t*)outp)[(size_t)row * ldo + col] = f2bf(v);
        } else {
          ushort_t h = f2bf(v);
          ushort_t* o = (ushort_t*)outp;
          o[(size_t)row * ldo + col] = h;
          o[(size_t)row * ldo + 2048 + col] = f2bf(v - bf2f(h));
        }
      }
    }
  }
}

// ---------------------------------------------------------------------------
// fp32 [R,Cn] -> bf16 [R,2Cn] hi|lo planes
__global__ __launch_bounds__(256) void split_hilo(
    const float* __restrict__ in, ushort_t* __restrict__ out, int R, int Cn)
{
  int total4 = R * (Cn >> 2);
  for (int i = blockIdx.x * 256 + threadIdx.x; i < total4; i += gridDim.x * 256) {
    int r = i / (Cn >> 2);
    int j = (i - r * (Cn >> 2)) * 4;
    floatx4 v = *(const floatx4*)&in[(size_t)r * Cn + j];
    shortx4 hi, lo;
#pragma unroll
    for (int t = 0; t < 4; ++t) {
      ushort_t h = f2bf(v[t]);
      hi[t] = (short)h;
      lo[t] = (short)f2bf(v[t] - bf2f(h));
    }
    *(shortx4*)&out[(size_t)r * 2 * Cn + j] = hi;
    *(shortx4*)&out[(size_t)r * 2 * Cn + Cn + j] = lo;
  }
}

// Wo fp32 [2048,2048] -> WoT2 bf16 [2048, 4096] = [Wo^T hi | Wo^T lo]
__global__ __launch_bounds__(256) void transpose_split(
    const float* __restrict__ in, ushort_t* __restrict__ out)
{
  __shared__ float t[32][33];
  int bx = blockIdx.x * 32, by = blockIdx.y * 32;
  int x = threadIdx.x;
  for (int i = threadIdx.y; i < 32; i += 8)
    t[i][x] = in[(size_t)(by + i) * 2048 + bx + x];
  __syncthreads();
  for (int i = threadIdx.y; i < 32; i += 8) {
    float v = t[x][i];                      // Wo[by+x][bx+i]: d=bx+i, e=by+x
    ushort_t h = f2bf(v);
    out[(size_t)(bx + i) * 4096 + (by + x)] = h;
    out[(size_t)(bx + i) * 4096 + 2048 + (by + x)] = f2bf(v - bf2f(h));
  }
}

__global__ __launch_bounds__(256) void build_sb(
    const float* __restrict__ bproj, const float* __restrict__ Cc,
    float* __restrict__ sb)
{
  int c = blockIdx.x;
  int cc = min(c, 999);
  float s = 0.f;
  for (int e = threadIdx.x; e < 2048; e += 256)
    s += bproj[e] * Cc[(size_t)cc * 2048 + e];
#pragma unroll
  for (int o = 32; o > 0; o >>= 1) s += __shfl_down(s, o, 64);
  __shared__ float red[4];
  int wave = threadIdx.x >> 6, lane = threadIdx.x & 63;
  if (lane == 0) red[wave] = s;
  __syncthreads();
  if (threadIdx.x == 0) sb[c] = red[0] + red[1] + red[2] + red[3];
}

// fp32 scores row [1024] -> bf16 probs row in-place (first 2KB of 4KB row).
// NaN-scrub + zero-sum guard retained as diagnostic hardening.
__global__ __launch_bounds__(256) void softmax_k(void* buf)
{
  int row = blockIdx.x;
  const float* s = (const float*)buf + (size_t)row * 1024;
  ushort_t*    p = (ushort_t*)buf + (size_t)row * 2048;
  int t = threadIdx.x;
  float v[4];
#pragma unroll
  for (int i = 0; i < 4; ++i) {
    int c = t + i * 256;
    float x = (c < 1000) ? s[c] : -3.0e38f;
    v[i] = (x == x) ? x : -3.0e38f;
  }
  float m = fmaxf(fmaxf(v[0], v[1]), fmaxf(v[2], v[3]));
#pragma unroll
  for (int o = 32; o > 0; o >>= 1) m = fmaxf(m, __shfl_xor(m, o, 64));
  __shared__ float redm[4], reds[4];
  int wave = t >> 6, lane = t & 63;
  if (lane == 0) redm[wave] = m;
  __syncthreads();
  m = fmaxf(fmaxf(redm[0], redm[1]), fmaxf(redm[2], redm[3]));
  float pv[4]; float sum = 0.f;
#pragma unroll
  for (int i = 0; i < 4; ++i) {
    int c = t + i * 256;
    pv[i] = (c < 1000) ? __expf(v[i] - m) : 0.f;
    sum += pv[i];
  }
#pragma unroll
  for (int o = 32; o > 0; o >>= 1) sum += __shfl_xor(sum, o, 64);
  if (lane == 0) reds[wave] = sum;
  __syncthreads();
  sum = reds[0] + reds[1] + reds[2] + reds[3];
  float inv = (sum > 0.f) ? 1.0f / sum : 0.f;
#pragma unroll
  for (int i = 0; i < 4; ++i) {
    int c = t + i * 256;
    p[c] = f2bf(pv[i] * inv);
  }
}

// ---------------------------------------------------------------------------
extern "C" void kernel_launch(void* const* d_in, const int* in_sizes, int n_in,
                              void* d_out, int out_size, void* d_ws, size_t ws_size,
                              hipStream_t stream)
{
  const float* H   = (const float*)d_in[0];  // [16384, 2048] fp32
  const float* Cc  = (const float*)d_in[1];  // [1000, 2048]  fp32
  const float* Wp  = (const float*)d_in[2];  // [2048, 2048]  fp32
  const float* bpj = (const float*)d_in[3];  // [2048]        fp32
  const float* Wo  = (const float*)d_in[4];  // [2048, 2048]  fp32
  const float* bo  = (const float*)d_in[5];  // [2048]        fp32
  float* out = (float*)d_out;                // [16384, 2048] fp32 (128MB)

  const size_t MB = (size_t)1 << 20;
  char* ws = (char*)d_ws;

  // persistent ws: CWT 4MB | sb 64KB | WpC2 8MB | H2 chunk | sp chunk
  ushort_t* CWT  = (ushort_t*)ws;
  float*    sb   = (float*)(ws + 4 * MB);
  ushort_t* WpC2 = (ushort_t*)(ws + 4 * MB + 65536);
  const size_t base2 = 12 * MB + 65536;

  // prepass scratch in d_out head (consumed before first out write):
  char* ob = (char*)d_out;
  ushort_t* C2   = (ushort_t*)ob;              // [1000 rows x 4096] bf16, ~7.8MB
  ushort_t* Wp2  = (ushort_t*)(ob + 8 * MB);   // [2048 x 4096] bf16, 16MB
  ushort_t* WoT2 = (ushort_t*)(ob + 24 * MB);  // [2048 x 4096] bf16, 16MB (ends 40MB)

  // chunk rows: largest cr with base2 + cr*12KB <= ws_size (floor 128)
  int cr = 128;
  for (int c = 4096; c >= 128; c >>= 1)
    if (ws_size >= base2 + (size_t)c * 12288) { cr = c; break; }
  ushort_t* H2 = (ushort_t*)(ws + base2);                 // [cr,4096] bf16
  void*     sp = (void*)(ws + base2 + (size_t)cr * 8192); // [cr,1024] fp32

  // --- prepasses ---
  split_hilo<<<dim3(2048), dim3(256), 0, stream>>>(Cc, C2, 1000, 2048);
  split_hilo<<<dim3(4096), dim3(256), 0, stream>>>(Wp, Wp2, 2048, 2048);
  transpose_split<<<dim3(64, 64), dim3(32, 8), 0, stream>>>(Wo, WoT2);
  build_sb<<<dim3(1024), dim3(256), 0, stream>>>(bpj, Cc, sb);
  // WpC2: A=C2 planes(Ch,Ch,Cl), B=Wp2 planes(Wh,Wl,Wh), K=6144 -> MODE2
  gemm_bt<2><<<dim3(8, 16), dim3(256), 0, stream>>>(
      C2, Wp2, WpC2, nullptr, 6144, 4096, 4096, 4096, 1000, 2048,
      2048, 2048, 4096, 4096);
  // CWT: A=WoT2(Th,Th,Tl), B=C2(Ch,Cl,Ch), K=6144 -> bf16 [2048,1024]
  gemm_bt<1><<<dim3(16, 8), dim3(256), 0, stream>>>(
      WoT2, C2, CWT, nullptr, 6144, 4096, 4096, 1024, 2048, 1000,
      2048, 2048, 4096, 4096);

  // --- chunked main loop ---
  const int nc = 16384 / cr;
  for (int c = 0; c < nc; ++c) {
    const float* Hc = H + (size_t)c * cr * 2048;
    float* outc = out + (size_t)c * cr * 2048;
    split_hilo<<<dim3(2048), dim3(256), 0, stream>>>(Hc, H2, cr, 2048);
    // scores: A=H2(Hh,Hh,Hl), B=WpC2(Wh,Wl,Wh), K=6144, fp32 + sb
    gemm_bt<0><<<dim3(cr / 128, 8), dim3(256), 0, stream>>>(
        H2, WpC2, sp, sb, 6144, 4096, 4096, 1024, cr, 1024,
        2048, 2048, 4096, 4096);
    softmax_k<<<dim3(cr), dim3(256), 0, stream>>>(sp);
    // out: A=probs bf16 (lda 2048 in-place), B=CWT, K=1024, fp32 out + bo
    gemm_bt<0><<<dim3(cr / 128, 16), dim3(256), 0, stream>>>(
        (const ushort_t*)sp, CWT, outc, bo, 1024, 2048, 1024, 2048, cr, 2048,
        1 << 30, 0, 1 << 30, 0);
  }
}